// Round 3
// baseline (6218.561 us; speedup 1.0000x reference)
//
#include <hip/hip_runtime.h>
#include <hip/hip_bf16.h>
#include <math.h>

#define NEGF (-1000000000.0f)

constexpr int Bc = 8;
constexpr int Sc = 64;
constexpr int Hc = 512;
constexpr int Tc = 17;
constexpr int TRIc = Sc*(Sc+1)/2;     // 2080
constexpr int G4 = 4*Hc;              // 2048

__device__ __forceinline__ int tri_idx(int i, int j){
  // row-major upper-tri index for (i<=j)
  return i*Sc - (i*(i-1))/2 + (j - i);
}

// masked pt value at (b,t,i,j); pt_acc holds raw accumulated projection (no bias)
__device__ __forceinline__ float pt_val(const float* __restrict__ pt_acc,
                                        const float* __restrict__ btv,
                                        int b, int t, int i, int j, int L){
  const bool masked = (i > j) || (j >= L) ||
                      (t < Tc-1 && i == j) || (t == Tc-1 && i < j);
  if (masked) return NEGF;
  return pt_acc[(((size_t)b*Tc + t)*Sc + i)*Sc + j] + btv[t];
}

// ---------------------------------------------------------------------------
// G = sv @ Wih^T   (M=16640, N=2048, K=512), output bf16
// grid (520, 8, 2): z=0 -> f, z=1 -> b.  block 256.
// ---------------------------------------------------------------------------
__global__ __launch_bounds__(256) void k_gemm_g(
    const float* __restrict__ sv,
    const float* __restrict__ Wih_f, const float* __restrict__ Wih_b,
    __hip_bfloat16* __restrict__ Gf, __hip_bfloat16* __restrict__ Gb)
{
  const int which = blockIdx.z;
  const float* Wm = which ? Wih_b : Wih_f;
  __hip_bfloat16* Gm = which ? Gb : Gf;
  const int m0 = blockIdx.x * 32;
  const int n0 = blockIdx.y * 256;
  const int t  = threadIdx.x;

  __shared__ float As[16][32];    // [k][m]
  __shared__ float Ws[16][260];   // [k][n], padded

  float acc[4][8];
  for (int a=0;a<4;a++)
    for (int c=0;c<8;c++) acc[a][c]=0.f;

  const int s0 = 4*(t>>5);
  const int c0 = 8*(t&31);

  for (int kc = 0; kc < Hc; kc += 16) {
    { // stage A tile (rows of sv)
      int m = t>>3, kk=(t&7)*2;
      const float2 v = *reinterpret_cast<const float2*>(sv + (size_t)(m0+m)*Hc + kc + kk);
      As[kk][m]=v.x; As[kk+1][m]=v.y;
    }
    { // stage W tile: thread t stages row n0+t, 16 consecutive k
      const float* wp = Wm + (size_t)(n0+t)*Hc + kc;
      #pragma unroll
      for (int q4=0;q4<4;q4++){
        float4 v = *reinterpret_cast<const float4*>(wp + 4*q4);
        Ws[4*q4+0][t]=v.x; Ws[4*q4+1][t]=v.y; Ws[4*q4+2][t]=v.z; Ws[4*q4+3][t]=v.w;
      }
    }
    __syncthreads();
    #pragma unroll
    for (int kk=0;kk<16;kk++){
      const float4 a = *reinterpret_cast<const float4*>(&As[kk][s0]);
      float av[4] = {a.x,a.y,a.z,a.w};
      float wv[8];
      *reinterpret_cast<float4*>(&wv[0]) = *reinterpret_cast<const float4*>(&Ws[kk][c0]);
      *reinterpret_cast<float4*>(&wv[4]) = *reinterpret_cast<const float4*>(&Ws[kk][c0+4]);
      #pragma unroll
      for (int si=0;si<4;si++){
        #pragma unroll
        for (int c=0;c<8;c++) acc[si][c] = fmaf(av[si], wv[c], acc[si][c]);
      }
    }
    __syncthreads();
  }
  #pragma unroll
  for (int si=0;si<4;si++){
    size_t row = (size_t)(m0+s0+si);
    #pragma unroll
    for (int c=0;c<8;c++)
      Gm[row*G4 + n0 + c0 + c] = __float2bfloat16(acc[si][c]);
  }
}

// ---------------------------------------------------------------------------
// One lockstep LSTM step for all 4 passes, with fused projection epilogue.
// pass 0: rows_b (F params, Gf) -> hi half, pos (r, L-1-k)
// pass 1: rows_f (B params, Gb) -> lo half, pos (r, r+k)
// pass 2: cols_b (B params, Gb) -> hi half, pos (r-k, r)
// pass 3: cols_f (F params, Gf) -> lo half, pos (k, r)
// grid (16,8,4), block 256. tile: 32 seqs x (4 gates x 64 hidden).
// ---------------------------------------------------------------------------
__global__ __launch_bounds__(256) void k_step(
    const float* __restrict__ Whh_f, const float* __restrict__ Whh_b,
    const float* __restrict__ bih_f, const float* __restrict__ bhh_f,
    const float* __restrict__ bih_b, const float* __restrict__ bhh_b,
    const __hip_bfloat16* __restrict__ Gf, const __hip_bfloat16* __restrict__ Gb,
    const int* __restrict__ lens, const float* __restrict__ Wt,
    float* __restrict__ PH, float* __restrict__ PC,
    float* __restrict__ pt_acc,
    int k)
{
  const int pass = blockIdx.z;
  const int mt   = blockIdx.x;      // 0..15
  const int nsl  = blockIdx.y;      // 0..7
  const int h0   = nsl*64;
  const int b    = mt>>1;
  const int r0   = (mt&1)*32;
  const int L    = lens[b];

  const bool rowpass = (pass < 2);
  if (rowpass) { if (r0 >= L - k) return; }
  else         { if (r0 + 31 < k || r0 >= L) return; }

  const bool useF = (pass==0 || pass==3);
  const float* W  = useF ? Whh_f : Whh_b;
  const float* b1 = useF ? bih_f : bih_b;
  const float* b2 = useF ? bhh_f : bhh_b;
  const __hip_bfloat16* G = useF ? Gf : Gb;

  const int cur = k & 1, nxt = cur ^ 1;
  // PH layout: [2][4][512][512]; PC: [4][512][512]
  float* Hcur = PH + (((size_t)cur*4 + pass)*512 + b*64 + r0)*Hc;
  float* Hnxt = PH + (((size_t)nxt*4 + pass)*512 + b*64 + r0)*Hc;
  float* Cst  = PC + (((size_t)pass*512) + b*64 + r0)*Hc;

  const int t  = threadIdx.x;
  __shared__ float Hs[16][32];
  __shared__ float Ws[16][260];

  float acc[4][8];  // [si][gate*2+du]
  for (int a=0;a<4;a++)
    for (int c=0;c<8;c++) acc[a][c]=0.f;

  const int s0 = 4*(t>>5);
  const int u0 = 2*(t&31);
  const int wrow = (t>>6)*Hc + h0 + (t&63);  // global Whh row staged by thread t

  for (int kc=0; kc<Hc; kc+=16){
    { int s=t>>3, kk=(t&7)*2;
      const float2 v = *reinterpret_cast<const float2*>(Hcur + (size_t)s*Hc + kc + kk);
      Hs[kk][s]=v.x; Hs[kk+1][s]=v.y; }
    { const float* wp = W + (size_t)wrow*Hc + kc;
      #pragma unroll
      for (int q4=0;q4<4;q4++){
        float4 v = *reinterpret_cast<const float4*>(wp + 4*q4);
        Ws[4*q4+0][t]=v.x; Ws[4*q4+1][t]=v.y; Ws[4*q4+2][t]=v.z; Ws[4*q4+3][t]=v.w; }
    }
    __syncthreads();
    #pragma unroll
    for (int kk=0;kk<16;kk++){
      const float4 a = *reinterpret_cast<const float4*>(&Hs[kk][s0]);
      float av[4] = {a.x,a.y,a.z,a.w};
      const float2 w0 = *reinterpret_cast<const float2*>(&Ws[kk][      u0]);
      const float2 w1 = *reinterpret_cast<const float2*>(&Ws[kk][ 64 + u0]);
      const float2 w2 = *reinterpret_cast<const float2*>(&Ws[kk][128 + u0]);
      const float2 w3 = *reinterpret_cast<const float2*>(&Ws[kk][192 + u0]);
      float wv[8] = {w0.x,w0.y,w1.x,w1.y,w2.x,w2.y,w3.x,w3.y};
      #pragma unroll
      for (int si=0;si<4;si++){
        #pragma unroll
        for (int c=0;c<8;c++) acc[si][c] = fmaf(av[si], wv[c], acc[si][c]);
      }
    }
    __syncthreads();
  }

  // ---- epilogue: gates -> cell -> fused 17-way projection ------------------
  const int u_ = h0 + u0;                       // first of this thread's 2 hidden idx
  const int off_wt = (pass==0 || pass==2) ? 512 : 0;   // hi half for *_b passes
  float wt0[Tc], wt1[Tc];
  #pragma unroll
  for (int tt=0; tt<Tc; tt++){
    wt0[tt] = Wt[(size_t)tt*(2*Hc) + off_wt + u_];
    wt1[tt] = Wt[(size_t)tt*(2*Hc) + off_wt + u_ + 1];
  }
  float bsum[4][2];
  #pragma unroll
  for (int g=0; g<4; g++){
    bsum[g][0] = b1[g*Hc + u_]     + b2[g*Hc + u_];
    bsum[g][1] = b1[g*Hc + u_ + 1] + b2[g*Hc + u_ + 1];
  }
  const int lane5 = t & 31;

  #pragma unroll
  for (int si=0;si<4;si++){
    const int s = s0 + si;      // within tile (uniform over the 32-lane group)
    const int r = r0 + s;       // 0..63
    bool act = rowpass ? (r < L - k) : (r >= k && r < L);
    if (!act) continue;
    int i, j, yi, yj;
    if      (pass==0){ i=r;   j=L-1-k; yi=r;   yj=j; }
    else if (pass==1){ i=r;   j=r+k;   yi=r;   yj=j; }
    else if (pass==2){ i=r-k; j=r;     yi=i;   yj=r; }
    else             { i=k;   j=r;     yi=k;   yj=r; }
    const size_t gro = ((size_t)b*TRIc + tri_idx(i,j))*G4;

    float hn[2];
    #pragma unroll
    for (int du=0; du<2; du++){
      const int u = u_ + du;
      float gi = acc[si][0+du] + __bfloat162float(G[gro +        u]) + bsum[0][du];
      float gf = acc[si][2+du] + __bfloat162float(G[gro +  512 + u]) + bsum[1][du];
      float gg = acc[si][4+du] + __bfloat162float(G[gro + 1024 + u]) + bsum[2][du];
      float go = acc[si][6+du] + __bfloat162float(G[gro + 1536 + u]) + bsum[3][du];
      float ii = 1.f/(1.f + expf(-gi));
      float ff = 1.f/(1.f + expf(-gf));
      float gt = tanhf(gg);
      float oo = 1.f/(1.f + expf(-go));
      float co = Cst[(size_t)s*Hc + u];
      float cn = ff*co + ii*gt;
      float hv = oo*tanhf(cn);
      Cst [(size_t)s*Hc + u] = cn;
      Hnxt[(size_t)s*Hc + u] = hv;
      hn[du] = hv;
    }
    // project this thread's 2 hidden values onto 17 labels, reduce over the
    // 32-lane group (u slice of 64), one atomic per (group, label)
    #pragma unroll
    for (int tt=0; tt<Tc; tt++){
      float sc = fmaf(hn[0], wt0[tt], hn[1]*wt1[tt]);
      sc += __shfl_xor(sc, 1);
      sc += __shfl_xor(sc, 2);
      sc += __shfl_xor(sc, 4);
      sc += __shfl_xor(sc, 8);
      sc += __shfl_xor(sc, 16);
      if (lane5 == 0)
        atomicAdd(&pt_acc[(((size_t)b*Tc + tt)*Sc + yi)*Sc + yj], sc);
    }
  }
}

// labeled[b,i,j] = logsumexp_t of masked pt
__global__ void k_lse(const float* __restrict__ pt_acc, const float* __restrict__ btv,
                      const int* __restrict__ lens, float* __restrict__ lab){
  const int idx = blockIdx.x*256 + threadIdx.x;  // 32768
  const int b = idx >> 12, ij = idx & 4095;
  const int i = ij >> 6, j = ij & 63;
  const int L = lens[b];
  float vs[Tc]; float m = -INFINITY;
  #pragma unroll
  for (int t=0;t<Tc;t++){ vs[t] = pt_val(pt_acc, btv, b, t, i, j, L); m = fmaxf(m, vs[t]); }
  float ssum = 0.f;
  #pragma unroll
  for (int t=0;t<Tc;t++) ssum += expf(vs[t]-m);
  lab[idx] = m + logf(ssum);
}

// matrix-tree slogdet per batch; one 64-thread block per b. double LU in LDS.
__global__ void k_logz(const float* __restrict__ lab, const int* __restrict__ lens,
                       float* __restrict__ out)
{
  __shared__ double Md[64][65];
  __shared__ double csum[64];
  __shared__ double root[64];
  const int b = blockIdx.x;
  const int L = lens[b];
  const int r = threadIdx.x;   // lane = row (mostly)

  for (int c=0;c<64;c++){
    float lv = lab[((size_t)b*Sc + r)*Sc + c];
    double a;
    if (r == c) a = 0.0;
    else { a = 1e-5; if (r < L && c < L) a += exp((double)lv); }
    Md[r][c] = a;
  }
  __syncthreads();
  { // lane as column index
    double cs = 0.0;
    for (int rr=0; rr<64; rr++) cs += Md[rr][r];
    csum[r] = cs;
    root[r] = (r < L) ? exp((double)lab[((size_t)b*Sc + r)*Sc + r]) : 0.0;
  }
  __syncthreads();
  for (int c=0;c<64;c++){
    double v;
    if (r == 0) v = root[c];
    else { v = -Md[r][c]; if (r == c) v += csum[c] + ((c >= L) ? 1.0 : 0.0); }
    Md[r][c] = v;
  }
  __syncthreads();

  double logdet = 0.0;
  for (int p=0; p<64; p++){
    double v = (r >= p) ? fabs(Md[r][p]) : -1.0;
    int idxv = r;
    #pragma unroll
    for (int off=32; off>0; off>>=1){
      double ov = __shfl_xor(v, off);
      int    oi = __shfl_xor(idxv, off);
      if (ov > v || (ov == v && oi < idxv)) { v = ov; idxv = oi; }
    }
    if (idxv != p){ // swap rows p, idxv: lane = column
      double tmp = Md[p][r]; Md[p][r] = Md[idxv][r]; Md[idxv][r] = tmp;
    }
    __syncthreads();
    const double diag = Md[p][p];
    logdet += log(fabs(diag));
    if (r > p){
      double f = Md[r][p] / diag;
      for (int c=p+1; c<64; c++) Md[r][c] -= f * Md[p][c];
    }
    __syncthreads();
  }
  if (r == 0) out[(size_t)Bc*Tc*65*65 + b] = (float)logdet;
}

// pe = _expand_matrix(masked pt)
__global__ void k_out(const float* __restrict__ pt_acc, const float* __restrict__ btv,
                      const int* __restrict__ lens, float* __restrict__ out){
  const int idx = blockIdx.x*256 + threadIdx.x;
  if (idx >= Bc*Tc*65*65) return;
  const int cc = idx % 65; int tmp = idx / 65;
  const int rr = tmp % 65; tmp /= 65;
  const int t  = tmp % Tc; const int b = tmp / Tc;
  float v;
  if (rr == cc) v = 0.f;
  else if (cc == 0) v = NEGF;
  else {
    const int i = (rr == 0) ? (cc-1) : (rr-1);
    v = pt_val(pt_acc, btv, b, t, i, cc-1, lens[b]);
  }
  out[idx] = v;
}

__global__ void k_zero_out(float* out, int n){
  int i = blockIdx.x*256 + threadIdx.x;
  if (i < n) out[i] = 0.f;
}

// ---------------------------------------------------------------------------
extern "C" void kernel_launch(void* const* d_in, const int* in_sizes, int n_in,
                              void* d_out, int out_size, void* d_ws, size_t ws_size,
                              hipStream_t stream)
{
  (void)in_sizes; (void)n_in;
  const int*   lens  = (const int*)  d_in[2];
  const float* sv    = (const float*)d_in[3];
  const float* Wih_f = (const float*)d_in[5];
  const float* Whh_f = (const float*)d_in[6];
  const float* bih_f = (const float*)d_in[7];
  const float* bhh_f = (const float*)d_in[8];
  const float* Wih_b = (const float*)d_in[9];
  const float* Whh_b = (const float*)d_in[10];
  const float* bih_b = (const float*)d_in[11];
  const float* bhh_b = (const float*)d_in[12];
  const float* Wt    = (const float*)d_in[13];
  const float* btv   = (const float*)d_in[14];

  const size_t G_BYTES  = (size_t)Bc*TRIc*G4*2;       // bf16  (68.2 MB each)
  const size_t PT_BYTES = (size_t)Bc*Tc*Sc*Sc*4;      // 2.23 MB
  const size_t PH_BYTES = (size_t)2*4*512*512*4;      // 8.39 MB
  const size_t PC_BYTES = (size_t)4*512*512*4;        // 4.19 MB
  const size_t LAB_BYTES= (size_t)Bc*Sc*Sc*4;         // 0.52 MB
  const size_t NEED = 2*G_BYTES + PT_BYTES + PH_BYTES + PC_BYTES + LAB_BYTES + 4096;

  if (ws_size < NEED) {
    // diagnostic fallback: clean absmax failure instead of a memory-fault abort
    k_zero_out<<<dim3((out_size+255)/256), 256, 0, stream>>>((float*)d_out, out_size);
    return;
  }

  char* base = (char*)d_ws;
  size_t off = 0;
  auto take = [&](size_t bytes)->char*{
    char* r = base + off; off += (bytes + 255) & ~(size_t)255; return r; };

  __hip_bfloat16* Gf = (__hip_bfloat16*)take(G_BYTES);
  __hip_bfloat16* Gb = (__hip_bfloat16*)take(G_BYTES);
  float* pt_acc = (float*)take(PT_BYTES);
  float* PH  = (float*)take(PH_BYTES);
  float* PC  = (float*)take(PC_BYTES);
  float* lab = (float*)take(LAB_BYTES);

  // zero pt_acc..PC (contiguous)
  (void)hipMemsetAsync(pt_acc, 0, PT_BYTES + PH_BYTES + PC_BYTES, stream);

  k_gemm_g<<<dim3(520,8,2), 256, 0, stream>>>(sv, Wih_f, Wih_b, Gf, Gb);

  for (int k=0; k<Sc; k++)
    k_step<<<dim3(16,8,4), 256, 0, stream>>>(Whh_f, Whh_b, bih_f, bhh_f, bih_b, bhh_b,
                                             Gf, Gb, lens, Wt, PH, PC, pt_acc, k);

  k_lse <<<dim3(128),  256, 0, stream>>>(pt_acc, btv, lens, lab);
  k_out <<<dim3((Bc*Tc*65*65 + 255)/256), 256, 0, stream>>>(pt_acc, btv, lens, (float*)d_out);
  k_logz<<<dim3(Bc), 64, 0, stream>>>(lab, lens, (float*)d_out);
}

// Round 4
// 2479.922 us; speedup vs baseline: 2.5076x; 2.5076x over previous
//
#include <hip/hip_runtime.h>
#include <hip/hip_bf16.h>
#include <math.h>

#define NEGF (-1000000000.0f)

constexpr int Bc = 8;
constexpr int Sc = 64;
constexpr int Hc = 512;
constexpr int Tc = 17;
constexpr int TRIc = Sc*(Sc+1)/2;     // 2080

typedef __bf16 bf16x8 __attribute__((ext_vector_type(8)));
typedef float  f32x4  __attribute__((ext_vector_type(4)));

__device__ __forceinline__ int tri_idx(int i, int j){
  return i*Sc - (i*(i-1))/2 + (j - i);
}

// (i,j) position + activity for (pass, row r, step k, length L).
// Output position (yi,yj) == (i,j) for all passes.
__device__ __forceinline__ void posmap(int pass, int r, int k, int L,
                                       int& i, int& j, bool& act){
  if      (pass == 0){ act = (r < L - k);            i = r;     j = L - 1 - k; }
  else if (pass == 1){ act = (r < L - k);            i = r;     j = r + k;     }
  else if (pass == 2){ act = (r >= k) && (r < L);    i = r - k; j = r;         }
  else               { act = (r >= k) && (r < L);    i = k;     j = r;         }
  if (!act){ i = 0; j = 0; }
}

// masked pt value at (b,t,i,j); pt_acc holds raw accumulated projection (no bias)
__device__ __forceinline__ float pt_val(const float* __restrict__ pt_acc,
                                        const float* __restrict__ btv,
                                        int b, int t, int i, int j, int L){
  const bool masked = (i > j) || (j >= L) ||
                      (t < Tc-1 && i == j) || (t == Tc-1 && i < j);
  if (masked) return NEGF;
  return pt_acc[(((size_t)b*Tc + t)*Sc + i)*Sc + j] + btv[t];
}

// ---------------------------------------------------------------------------
// fp32 -> bf16 conversion (vectorized by 4)
// ---------------------------------------------------------------------------
__global__ __launch_bounds__(256) void k_cvt(const float* __restrict__ s,
                                             __hip_bfloat16* __restrict__ d, int n4){
  int i = blockIdx.x*256 + threadIdx.x;
  if (i >= n4) return;
  float4 v = reinterpret_cast<const float4*>(s)[i];
  union { __hip_bfloat16 h[4]; ushort4 u; } p;
  p.h[0] = __float2bfloat16(v.x); p.h[1] = __float2bfloat16(v.y);
  p.h[2] = __float2bfloat16(v.z); p.h[3] = __float2bfloat16(v.w);
  reinterpret_cast<ushort4*>(d)[i] = p.u;
}

// ---------------------------------------------------------------------------
// One lockstep LSTM step for all 4 passes, fused input-GEMM (K = 512 H + 512 X),
// bf16 MFMA, fp32 cell, MFMA-based 17-label projection epilogue.
// grid (8 u-slices, 8 b, 4 passes), block 512 (8 waves).
// Block: 64 seqs x (4 gates x 64 units). Wave (mgrp=wv>>2, ngrp=wv&3):
//   2 M-tiles (32 seqs) x 4 gate-tiles at unit-slot ngrp (16 units).
// ---------------------------------------------------------------------------
__global__ __launch_bounds__(512) void k_step2(
    const __hip_bfloat16* __restrict__ Whh_f, const __hip_bfloat16* __restrict__ Wih_f,
    const __hip_bfloat16* __restrict__ Whh_b, const __hip_bfloat16* __restrict__ Wih_b,
    const float* __restrict__ bih_f, const float* __restrict__ bhh_f,
    const float* __restrict__ bih_b, const float* __restrict__ bhh_b,
    const __hip_bfloat16* __restrict__ svb, const __hip_bfloat16* __restrict__ Wtb,
    const int* __restrict__ lens,
    __hip_bfloat16* __restrict__ H, float* __restrict__ C,
    float* __restrict__ pt_acc, int k)
{
  const int u8   = blockIdx.x;        // 0..7 : 64-unit slice
  const int b    = blockIdx.y;
  const int pass = blockIdx.z;
  const int L    = lens[b];
  if (k >= L) return;                 // all passes inactive for k >= L

  const int u_base = u8*64;
  const bool useF = (pass==0 || pass==3);
  const __hip_bfloat16* Whh = useF ? Whh_f : Whh_b;
  const __hip_bfloat16* Wih = useF ? Wih_f : Wih_b;
  const float* b1 = useF ? bih_f : bih_b;
  const float* b2 = useF ? bhh_f : bhh_b;
  const int off_wt = (pass==0 || pass==2) ? 512 : 0;   // hi half for *_b passes

  const int t    = threadIdx.x;
  const int lane = t & 63;
  const int wv   = t >> 6;            // 0..7
  const int c15  = lane & 15;
  const int qq   = lane >> 4;         // 0..3
  const int mgrp = wv >> 2;           // 0..1
  const int ngrp = wv & 3;            // 0..3

  // B tiles: row = q*64 + gate*16 + rr  (q = unit-slot 0..3, rr = unit 0..15)
  // padded to 72 bf16 per row (144 B) -> uniform bank spread for b128 ops
  __shared__ __hip_bfloat16 Bl[2][256*72];
  __shared__ __hip_bfloat16 hbuf[64*72];

  const int cur = k & 1;
  const __hip_bfloat16* Hcur = H + ((((size_t)cur*4 + pass)*8 + b)*64)*Hc;
  __hip_bfloat16*       Hnxt = H + ((((size_t)(cur^1)*4 + pass)*8 + b)*64)*Hc;
  float* Cb = C + (((size_t)pass*8 + b)*64)*Hc;

  // A-operand row pointers (rows mgrp*32 + mt*16 + c15)
  const __hip_bfloat16* haptr[2];
  const __hip_bfloat16* xaptr[2];
  #pragma unroll
  for (int mt=0; mt<2; ++mt){
    int r = mgrp*32 + mt*16 + c15;
    int i, j; bool act;
    posmap(pass, r, k, L, i, j, act);
    haptr[mt] = Hcur + (size_t)r*Hc;
    xaptr[mt] = svb + ((size_t)b*TRIc + tri_idx(i,j))*Hc;
  }

  int4 stg[4];
  auto ldg = [&](int c){
    const __hip_bfloat16* Wsrc = (c < 8) ? Whh : Wih;
    const int k0 = (c & 7)*64;
    #pragma unroll
    for (int rd=0; rd<4; ++rd){
      int row  = rd*64 + (t>>3);
      int q    = row>>6, gate = (row>>4)&3, rr = row&15;
      int wr   = gate*512 + u_base + q*16 + rr;
      stg[rd] = *reinterpret_cast<const int4*>(Wsrc + (size_t)wr*Hc + k0 + (t&7)*8);
    }
  };
  auto stl = [&](int buf){
    #pragma unroll
    for (int rd=0; rd<4; ++rd){
      int row = rd*64 + (t>>3);
      *reinterpret_cast<int4*>(&Bl[buf][row*72 + (t&7)*8]) = stg[rd];
    }
  };

  bf16x8 a[2][2], an[2][2];           // [kk][mt]
  auto lda = [&](int c, bf16x8 (&dst)[2][2]){
    #pragma unroll
    for (int kk=0; kk<2; ++kk)
      #pragma unroll
      for (int mt=0; mt<2; ++mt){
        const __hip_bfloat16* p = (c < 8) ? (haptr[mt] + c*64) : (xaptr[mt] + (c-8)*64);
        dst[kk][mt] = *reinterpret_cast<const bf16x8*>(p + kk*32 + qq*8);
      }
  };

  f32x4 acc[2][4];                    // [mt][gate]
  #pragma unroll
  for (int mt=0; mt<2; ++mt)
    #pragma unroll
    for (int g=0; g<4; ++g) acc[mt][g] = f32x4{0.f,0.f,0.f,0.f};

  ldg(0); stl(0); lda(0, a);
  __syncthreads();

  #pragma unroll
  for (int c=0; c<16; ++c){
    if (c < 15){ ldg(c+1); lda(c+1, an); }
    const int buf = c & 1;
    #pragma unroll
    for (int kk=0; kk<2; ++kk){
      #pragma unroll
      for (int g=0; g<4; ++g){
        bf16x8 bf = *reinterpret_cast<const bf16x8*>(
            &Bl[buf][(ngrp*64 + g*16 + c15)*72 + kk*32 + qq*8]);
        acc[0][g] = __builtin_amdgcn_mfma_f32_16x16x32_bf16(a[kk][0], bf, acc[0][g], 0,0,0);
        acc[1][g] = __builtin_amdgcn_mfma_f32_16x16x32_bf16(a[kk][1], bf, acc[1][g], 0,0,0);
      }
    }
    if (c < 15){
      stl(buf ^ 1);
      #pragma unroll
      for (int kk=0; kk<2; ++kk)
        #pragma unroll
        for (int mt=0; mt<2; ++mt) a[kk][mt] = an[kk][mt];
    }
    __syncthreads();
  }

  // ---- cell epilogue: D[row][unit]: row = m*16 + qq*4 + e, unit = ubase+ngrp*16+c15
  const int u = u_base + ngrp*16 + c15;
  const float bsI = b1[u]        + b2[u];
  const float bsF = b1[512 + u]  + b2[512 + u];
  const float bsG = b1[1024 + u] + b2[1024 + u];
  const float bsO = b1[1536 + u] + b2[1536 + u];

  #pragma unroll
  for (int mt=0; mt<2; ++mt){
    #pragma unroll
    for (int e=0; e<4; ++e){
      int row = mgrp*32 + mt*16 + qq*4 + e;
      int i, j; bool act;
      posmap(pass, row, k, L, i, j, act);
      float hv = 0.f;
      if (act){
        float gi = acc[mt][0][e] + bsI;
        float gf = acc[mt][1][e] + bsF;
        float gg = acc[mt][2][e] + bsG;
        float go = acc[mt][3][e] + bsO;
        float ii = 1.f/(1.f + expf(-gi));
        float ff = 1.f/(1.f + expf(-gf));
        float gt = tanhf(gg);
        float oo = 1.f/(1.f + expf(-go));
        float cn = ff*Cb[(size_t)row*Hc + u] + ii*gt;
        hv = oo*tanhf(cn);
        Cb  [(size_t)row*Hc + u] = cn;
        Hnxt[(size_t)row*Hc + u] = __float2bfloat16(hv);
      }
      hbuf[row*72 + ngrp*16 + c15] = __float2bfloat16(hv);
    }
  }
  __syncthreads();

  // ---- projection epilogue: pt[row][tt] += h[row][64u] . Wt[tt][64u]  (MFMA)
  const int m4 = wv & 3;              // M-tile 0..3
  const int nt = wv >> 2;             // label-tile 0..1
  const int ttc = nt*16 + c15;
  bf16x8 wb[2];
  #pragma unroll
  for (int kt=0; kt<2; ++kt){
    if (ttc < Tc)
      wb[kt] = *reinterpret_cast<const bf16x8*>(
          Wtb + (size_t)ttc*1024 + off_wt + u_base + kt*32 + qq*8);
    else {
      union { int4 i4; bf16x8 v; } z; z.i4 = make_int4(0,0,0,0); wb[kt] = z.v;
    }
  }
  f32x4 pr = f32x4{0.f,0.f,0.f,0.f};
  #pragma unroll
  for (int kt=0; kt<2; ++kt){
    bf16x8 ha = *reinterpret_cast<const bf16x8*>(
        &hbuf[(m4*16 + c15)*72 + kt*32 + qq*8]);
    pr = __builtin_amdgcn_mfma_f32_16x16x32_bf16(ha, wb[kt], pr, 0,0,0);
  }
  if (ttc < Tc){
    #pragma unroll
    for (int e=0; e<4; ++e){
      int row = m4*16 + qq*4 + e;
      int i, j; bool act;
      posmap(pass, row, k, L, i, j, act);
      if (act)
        atomicAdd(&pt_acc[(((size_t)b*Tc + ttc)*Sc + i)*Sc + j], pr[e]);
    }
  }
}

// labeled[b,i,j] = logsumexp_t of masked pt
__global__ void k_lse(const float* __restrict__ pt_acc, const float* __restrict__ btv,
                      const int* __restrict__ lens, float* __restrict__ lab){
  const int idx = blockIdx.x*256 + threadIdx.x;  // 32768
  const int b = idx >> 12, ij = idx & 4095;
  const int i = ij >> 6, j = ij & 63;
  const int L = lens[b];
  float vs[Tc]; float m = -INFINITY;
  #pragma unroll
  for (int t=0;t<Tc;t++){ vs[t] = pt_val(pt_acc, btv, b, t, i, j, L); m = fmaxf(m, vs[t]); }
  float ssum = 0.f;
  #pragma unroll
  for (int t=0;t<Tc;t++) ssum += expf(vs[t]-m);
  lab[idx] = m + logf(ssum);
}

// matrix-tree slogdet per batch; one 64-thread block per b. double LU in LDS.
__global__ void k_logz(const float* __restrict__ lab, const int* __restrict__ lens,
                       float* __restrict__ out)
{
  __shared__ double Md[64][65];
  __shared__ double csum[64];
  __shared__ double root[64];
  const int b = blockIdx.x;
  const int L = lens[b];
  const int r = threadIdx.x;

  for (int c=0;c<64;c++){
    float lv = lab[((size_t)b*Sc + r)*Sc + c];
    double a;
    if (r == c) a = 0.0;
    else { a = 1e-5; if (r < L && c < L) a += exp((double)lv); }
    Md[r][c] = a;
  }
  __syncthreads();
  {
    double cs = 0.0;
    for (int rr=0; rr<64; rr++) cs += Md[rr][r];
    csum[r] = cs;
    root[r] = (r < L) ? exp((double)lab[((size_t)b*Sc + r)*Sc + r]) : 0.0;
  }
  __syncthreads();
  for (int c=0;c<64;c++){
    double v;
    if (r == 0) v = root[c];
    else { v = -Md[r][c]; if (r == c) v += csum[c] + ((c >= L) ? 1.0 : 0.0); }
    Md[r][c] = v;
  }
  __syncthreads();

  double logdet = 0.0;
  for (int p=0; p<64; p++){
    double v = (r >= p) ? fabs(Md[r][p]) : -1.0;
    int idxv = r;
    #pragma unroll
    for (int off=32; off>0; off>>=1){
      double ov = __shfl_xor(v, off);
      int    oi = __shfl_xor(idxv, off);
      if (ov > v || (ov == v && oi < idxv)) { v = ov; idxv = oi; }
    }
    if (idxv != p){
      double tmp = Md[p][r]; Md[p][r] = Md[idxv][r]; Md[idxv][r] = tmp;
    }
    __syncthreads();
    const double diag = Md[p][p];
    logdet += log(fabs(diag));
    if (r > p){
      double f = Md[r][p] / diag;
      for (int c=p+1; c<64; c++) Md[r][c] -= f * Md[p][c];
    }
    __syncthreads();
  }
  if (r == 0) out[(size_t)Bc*Tc*65*65 + b] = (float)logdet;
}

// pe = _expand_matrix(masked pt)
__global__ void k_out(const float* __restrict__ pt_acc, const float* __restrict__ btv,
                      const int* __restrict__ lens, float* __restrict__ out){
  const int idx = blockIdx.x*256 + threadIdx.x;
  if (idx >= Bc*Tc*65*65) return;
  const int cc = idx % 65; int tmp = idx / 65;
  const int rr = tmp % 65; tmp /= 65;
  const int t  = tmp % Tc; const int b = tmp / Tc;
  float v;
  if (rr == cc) v = 0.f;
  else if (cc == 0) v = NEGF;
  else {
    const int i = (rr == 0) ? (cc-1) : (rr-1);
    v = pt_val(pt_acc, btv, b, t, i, cc-1, lens[b]);
  }
  out[idx] = v;
}

__global__ void k_zero_out(float* out, int n){
  int i = blockIdx.x*256 + threadIdx.x;
  if (i < n) out[i] = 0.f;
}

// ---------------------------------------------------------------------------
extern "C" void kernel_launch(void* const* d_in, const int* in_sizes, int n_in,
                              void* d_out, int out_size, void* d_ws, size_t ws_size,
                              hipStream_t stream)
{
  (void)in_sizes; (void)n_in;
  const int*   lens  = (const int*)  d_in[2];
  const float* sv    = (const float*)d_in[3];
  const float* Wih_f = (const float*)d_in[5];
  const float* Whh_f = (const float*)d_in[6];
  const float* bih_f = (const float*)d_in[7];
  const float* bhh_f = (const float*)d_in[8];
  const float* Wih_b = (const float*)d_in[9];
  const float* Whh_b = (const float*)d_in[10];
  const float* bih_b = (const float*)d_in[11];
  const float* bhh_b = (const float*)d_in[12];
  const float* Wt    = (const float*)d_in[13];
  const float* btv   = (const float*)d_in[14];

  const size_t SVB  = (size_t)Bc*TRIc*Hc*2;     // 17.0 MB bf16
  const size_t WB   = (size_t)2048*512*2;       // 2.1 MB bf16 each
  const size_t WTB  = (size_t)Tc*1024*2;        // 34.8 KB
  const size_t PT   = (size_t)Bc*Tc*Sc*Sc*4;    // 2.23 MB
  const size_t HB   = (size_t)2*4*8*64*Hc*2;    // 4.19 MB bf16
  const size_t CB   = (size_t)4*8*64*Hc*4;      // 4.19 MB fp32
  const size_t LAB  = (size_t)Bc*Sc*Sc*4;       // 131 KB
  const size_t NEED = SVB + 4*WB + WTB + PT + HB + CB + LAB + 8192;

  if (ws_size < NEED) {
    k_zero_out<<<dim3((out_size+255)/256), 256, 0, stream>>>((float*)d_out, out_size);
    return;
  }

  char* base = (char*)d_ws;
  size_t off = 0;
  auto take = [&](size_t bytes)->char*{
    char* r = base + off; off += (bytes + 255) & ~(size_t)255; return r; };

  __hip_bfloat16* svb    = (__hip_bfloat16*)take(SVB);
  __hip_bfloat16* Whh_fb = (__hip_bfloat16*)take(WB);
  __hip_bfloat16* Wih_fb = (__hip_bfloat16*)take(WB);
  __hip_bfloat16* Whh_bb = (__hip_bfloat16*)take(WB);
  __hip_bfloat16* Wih_bb = (__hip_bfloat16*)take(WB);
  __hip_bfloat16* Wtb    = (__hip_bfloat16*)take(WTB);
  float* pt_acc = (float*)take(PT);
  __hip_bfloat16* H = (__hip_bfloat16*)take(HB);
  float* C   = (float*)take(CB);
  float* lab = (float*)take(LAB);

  // zero pt_acc + H + C (contiguous takes, each 256B-aligned size)
  (void)hipMemsetAsync(pt_acc, 0, PT + HB + CB, stream);

  // fp32 -> bf16 converts
  k_cvt<<<dim3((2129920+255)/256), 256, 0, stream>>>(sv,    svb,    2129920);
  k_cvt<<<dim3(1024), 256, 0, stream>>>(Whh_f, Whh_fb, 262144);
  k_cvt<<<dim3(1024), 256, 0, stream>>>(Wih_f, Wih_fb, 262144);
  k_cvt<<<dim3(1024), 256, 0, stream>>>(Whh_b, Whh_bb, 262144);
  k_cvt<<<dim3(1024), 256, 0, stream>>>(Wih_b, Wih_bb, 262144);
  k_cvt<<<dim3(17),   256, 0, stream>>>(Wt,    Wtb,    4352);

  for (int k=0; k<Sc; k++)
    k_step2<<<dim3(8,8,4), 512, 0, stream>>>(Whh_fb, Wih_fb, Whh_bb, Wih_bb,
                                             bih_f, bhh_f, bih_b, bhh_b,
                                             svb, Wtb, lens, H, C, pt_acc, k);

  k_lse <<<dim3(128), 256, 0, stream>>>(pt_acc, btv, lens, lab);
  k_out <<<dim3((Bc*Tc*65*65 + 255)/256), 256, 0, stream>>>(pt_acc, btv, lens, (float*)d_out);
  k_logz<<<dim3(Bc), 64, 0, stream>>>(lab, lens, (float*)d_out);
}

// Round 5
// 2339.360 us; speedup vs baseline: 2.6582x; 1.0601x over previous
//
#include <hip/hip_runtime.h>
#include <hip/hip_bf16.h>
#include <math.h>

#define NEGF (-1000000000.0f)

constexpr int Bc = 8;
constexpr int Sc = 64;
constexpr int Hc = 512;
constexpr int Tc = 17;
constexpr int TRIc = Sc*(Sc+1)/2;     // 2080

typedef __bf16 bf16x8 __attribute__((ext_vector_type(8)));
typedef float  f32x4  __attribute__((ext_vector_type(4)));

__device__ __forceinline__ int tri_idx(int i, int j){
  return i*Sc - (i*(i-1))/2 + (j - i);
}

// (i,j) position + activity for (pass, row r, step k, length L)
__device__ __forceinline__ void posmap(int pass, int r, int k, int L,
                                       int& i, int& j, bool& act){
  if      (pass == 0){ act = (r < L - k);            i = r;     j = L - 1 - k; }
  else if (pass == 1){ act = (r < L - k);            i = r;     j = r + k;     }
  else if (pass == 2){ act = (r >= k) && (r < L);    i = r - k; j = r;         }
  else               { act = (r >= k) && (r < L);    i = k;     j = r;         }
  if (!act){ i = 0; j = 0; }
}

__device__ __forceinline__ float pt_val(const float* __restrict__ pt_acc,
                                        const float* __restrict__ btv,
                                        int b, int t, int i, int j, int L){
  const bool masked = (i > j) || (j >= L) ||
                      (t < Tc-1 && i == j) || (t == Tc-1 && i < j);
  if (masked) return NEGF;
  return pt_acc[(((size_t)b*Tc + t)*Sc + i)*Sc + j] + btv[t];
}

// ---------------------------------------------------------------------------
// fp32 -> bf16 conversion (vectorized by 4)
// ---------------------------------------------------------------------------
__global__ __launch_bounds__(256) void k_cvt(const float* __restrict__ s,
                                             __hip_bfloat16* __restrict__ d, int n4){
  int i = blockIdx.x*256 + threadIdx.x;
  if (i >= n4) return;
  float4 v = reinterpret_cast<const float4*>(s)[i];
  union { __hip_bfloat16 h[4]; ushort4 u; } p;
  p.h[0] = __float2bfloat16(v.x); p.h[1] = __float2bfloat16(v.y);
  p.h[2] = __float2bfloat16(v.z); p.h[3] = __float2bfloat16(v.w);
  reinterpret_cast<ushort4*>(d)[i] = p.u;
}

// ---------------------------------------------------------------------------
// Weight prepack: Wp[wset][us][128][1024] bf16
//   row128 = g*32 + uu maps to W row g*512 + us*32 + uu;
//   col k: k<512 -> Whh[row][k], k>=512 -> Wih[row][k-512]
// ---------------------------------------------------------------------------
__global__ __launch_bounds__(256) void k_pack(
    const float* __restrict__ Whh_f, const float* __restrict__ Wih_f,
    const float* __restrict__ Whh_b, const float* __restrict__ Wih_b,
    __hip_bfloat16* __restrict__ Wp)
{
  int idx = blockIdx.x*256 + threadIdx.x;       // 1,048,576 total
  int k4  = idx & 255;                          // 256 groups of 4
  int row = (idx >> 8) & 127;
  int us  = (idx >> 15) & 15;
  int ws  = idx >> 19;
  int g = row >> 5, uu = row & 31;
  int srow = g*512 + us*32 + uu;
  int k = k4*4;
  const float* src;
  if (ws == 0) src = (k < 512) ? Whh_f : Wih_f;
  else         src = (k < 512) ? Whh_b : Wih_b;
  float4 v = *reinterpret_cast<const float4*>(src + (size_t)srow*512 + (k & 511));
  union { __hip_bfloat16 h[4]; ushort4 u; } p;
  p.h[0] = __float2bfloat16(v.x); p.h[1] = __float2bfloat16(v.y);
  p.h[2] = __float2bfloat16(v.z); p.h[3] = __float2bfloat16(v.w);
  *reinterpret_cast<ushort4*>(Wp + (size_t)idx*4) = p.u;
}

// ---------------------------------------------------------------------------
// Lockstep LSTM step. grid (16 u-slices, 4 b-pairs, 4 passes), block 512.
// Block tile: M=128 (2 batches x 64 rows), N=128 (4 gates x 32 units), K=1024.
// Wave w: M-rows [ (w>>2)*64 + (w&3)*16 .. +16 ), full N.
// ---------------------------------------------------------------------------
__global__ __launch_bounds__(512) void k_step3(
    const __hip_bfloat16* __restrict__ Wp,
    const float* __restrict__ bih_f, const float* __restrict__ bhh_f,
    const float* __restrict__ bih_b, const float* __restrict__ bhh_b,
    const __hip_bfloat16* __restrict__ svb, const __hip_bfloat16* __restrict__ Wtb,
    const int* __restrict__ lens,
    __hip_bfloat16* __restrict__ H, float* __restrict__ C,
    float* __restrict__ pt_acc, int k)
{
  const int us   = blockIdx.x;        // 0..15 : 32-unit slice
  const int bq   = blockIdx.y;        // 0..3  : batch pair
  const int pass = blockIdx.z;
  const int L0 = lens[bq*2], L1 = lens[bq*2+1];
  if (k >= max(L0, L1)) return;

  const bool useF = (pass==0 || pass==3);
  const int wset = useF ? 0 : 1;
  const float* b1 = useF ? bih_f : bih_b;
  const float* b2 = useF ? bhh_f : bhh_b;
  const int off_wt = (pass==0 || pass==2) ? 512 : 0;

  const int t    = threadIdx.x;
  const int lane = t & 63;
  const int wv   = t >> 6;            // 0..7
  const int c15  = lane & 15;
  const int qq   = lane >> 4;         // 0..3
  const int b_local = wv >> 2;        // 0..1
  const int mb      = (wv & 3) * 16;  // seq-row base within batch
  const int b  = bq*2 + b_local;
  const int L  = b_local ? L1 : L0;

  __shared__ __hip_bfloat16 Ws[2][128*72];   // W tile, 72-elem padded rows
  __shared__ __hip_bfloat16 hbuf[128*40];    // h out, 40-elem padded rows

  const int cur = k & 1;
  const __hip_bfloat16* Hcur = H + ((((size_t)cur*4 + pass)*8 + b)*64)*Hc;
  __hip_bfloat16*       Hnxt = H + ((((size_t)(cur^1)*4 + pass)*8 + b)*64)*Hc;
  float* Cb = C + (((size_t)pass*8 + b)*64)*Hc;

  // per-lane A row (row = mb + c15)
  const int arow = mb + c15;
  int ai, aj; bool aact;
  posmap(pass, arow, k, L, ai, aj, aact);
  const __hip_bfloat16* hptr = Hcur + (size_t)arow*Hc;
  const __hip_bfloat16* xptr = svb + ((size_t)b*TRIc + tri_idx(ai,aj))*Hc;

  const __hip_bfloat16* Wpb = Wp + ((size_t)wset*16 + us)*128*1024;

  int4 stg[2];
  auto ldg = [&](int c){
    #pragma unroll
    for (int rd=0; rd<2; ++rd){
      int e = rd*512 + t;             // 0..1023
      int row = e >> 3, g8 = e & 7;
      stg[rd] = *reinterpret_cast<const int4*>(Wpb + (size_t)row*1024 + c*64 + g8*8);
    }
  };
  auto stl = [&](int buf){
    #pragma unroll
    for (int rd=0; rd<2; ++rd){
      int e = rd*512 + t;
      int row = e >> 3, g8 = e & 7;
      *reinterpret_cast<int4*>(&Ws[buf][row*72 + g8*8]) = stg[rd];
    }
  };

  bf16x8 a[2], an[2];
  auto lda = [&](int c, bf16x8 (&dst)[2]){
    const __hip_bfloat16* p = (c < 8) ? hptr : xptr;
    const int off = (c & 7)*64 + qq*8;
    dst[0] = *reinterpret_cast<const bf16x8*>(p + off);
    dst[1] = *reinterpret_cast<const bf16x8*>(p + off + 32);
  };

  f32x4 acc[8];                       // frag f = g*2 + u16
  #pragma unroll
  for (int f=0; f<8; ++f) acc[f] = f32x4{0.f,0.f,0.f,0.f};

  ldg(0); stl(0); lda(0, a);
  __syncthreads();

  for (int c=0; c<16; ++c){
    if (c < 15){ ldg(c+1); lda(c+1, an); }
    const int buf = c & 1;
    #pragma unroll
    for (int kk=0; kk<2; ++kk){
      #pragma unroll
      for (int g=0; g<4; ++g){
        #pragma unroll
        for (int u16=0; u16<2; ++u16){
          bf16x8 bf = *reinterpret_cast<const bf16x8*>(
              &Ws[buf][(g*32 + u16*16 + c15)*72 + kk*32 + qq*8]);
          acc[g*2+u16] = __builtin_amdgcn_mfma_f32_16x16x32_bf16(a[kk], bf, acc[g*2+u16], 0,0,0);
        }
      }
    }
    if (c < 15){
      stl(buf ^ 1);
      a[0] = an[0]; a[1] = an[1];
    }
    __syncthreads();
  }

  // ---- cell epilogue: D[row=qq*4+e][col=c15] per frag ----------------------
  #pragma unroll
  for (int u16=0; u16<2; ++u16){
    const int u = us*32 + u16*16 + c15;
    const float bsI = b1[u]        + b2[u];
    const float bsF = b1[512 + u]  + b2[512 + u];
    const float bsG = b1[1024 + u] + b2[1024 + u];
    const float bsO = b1[1536 + u] + b2[1536 + u];
    #pragma unroll
    for (int e=0; e<4; ++e){
      const int r = mb + qq*4 + e;    // seq row
      int i, j; bool act;
      posmap(pass, r, k, L, i, j, act);
      float hv = 0.f;
      if (act){
        float gi = acc[0*2+u16][e] + bsI;
        float gf = acc[1*2+u16][e] + bsF;
        float gg = acc[2*2+u16][e] + bsG;
        float go = acc[3*2+u16][e] + bsO;
        float ii = 1.f/(1.f + expf(-gi));
        float ff = 1.f/(1.f + expf(-gf));
        float gt = tanhf(gg);
        float oo = 1.f/(1.f + expf(-go));
        float cn = ff*Cb[(size_t)r*Hc + u] + ii*gt;
        hv = oo*tanhf(cn);
        Cb  [(size_t)r*Hc + u] = cn;
        Hnxt[(size_t)r*Hc + u] = __float2bfloat16(hv);
      }
      hbuf[(b_local*64 + mb + qq*4 + e)*40 + u16*16 + c15] = __float2bfloat16(hv);
    }
  }
  __syncthreads();

  // ---- projection epilogue: pr[row][t] = h[row][32u] . Wt[t][32u] ---------
  bf16x8 wb0, wb1;
  wb0 = *reinterpret_cast<const bf16x8*>(
      Wtb + (size_t)c15*1024 + off_wt + us*32 + qq*8);
  {
    union { int4 i4; bf16x8 v; } z; z.i4 = make_int4(0,0,0,0);
    wb1 = (c15 == 0)
        ? *reinterpret_cast<const bf16x8*>(Wtb + (size_t)16*1024 + off_wt + us*32 + qq*8)
        : z.v;
  }
  bf16x8 ha = *reinterpret_cast<const bf16x8*>(
      &hbuf[(b_local*64 + mb + c15)*40 + qq*8]);
  f32x4 pr0 = f32x4{0.f,0.f,0.f,0.f};
  f32x4 pr1 = f32x4{0.f,0.f,0.f,0.f};
  pr0 = __builtin_amdgcn_mfma_f32_16x16x32_bf16(ha, wb0, pr0, 0,0,0);
  pr1 = __builtin_amdgcn_mfma_f32_16x16x32_bf16(ha, wb1, pr1, 0,0,0);

  #pragma unroll
  for (int e=0; e<4; ++e){
    const int r = mb + qq*4 + e;
    int i, j; bool act;
    posmap(pass, r, k, L, i, j, act);
    if (act){
      atomicAdd(&pt_acc[(((size_t)b*Tc + c15)*Sc + i)*Sc + j], pr0[e]);
      if (c15 == 0)
        atomicAdd(&pt_acc[(((size_t)b*Tc + 16)*Sc + i)*Sc + j], pr1[e]);
    }
  }
}

// labeled[b,i,j] = logsumexp_t of masked pt
__global__ void k_lse(const float* __restrict__ pt_acc, const float* __restrict__ btv,
                      const int* __restrict__ lens, float* __restrict__ lab){
  const int idx = blockIdx.x*256 + threadIdx.x;  // 32768
  const int b = idx >> 12, ij = idx & 4095;
  const int i = ij >> 6, j = ij & 63;
  const int L = lens[b];
  float vs[Tc]; float m = -INFINITY;
  #pragma unroll
  for (int t=0;t<Tc;t++){ vs[t] = pt_val(pt_acc, btv, b, t, i, j, L); m = fmaxf(m, vs[t]); }
  float ssum = 0.f;
  #pragma unroll
  for (int t=0;t<Tc;t++) ssum += expf(vs[t]-m);
  lab[idx] = m + logf(ssum);
}

// matrix-tree slogdet per batch; 256 threads: thread = (col c, row-group rg)
__global__ __launch_bounds__(256) void k_logz(
    const float* __restrict__ lab, const int* __restrict__ lens,
    float* __restrict__ out)
{
  __shared__ double Md[64][65];
  __shared__ double part[4][64];
  __shared__ double rootv[64];
  __shared__ int spiv;
  const int b = blockIdx.x;
  const int L = lens[b];
  const int tid = threadIdx.x;
  const int c  = tid & 63;
  const int rg = tid >> 6;

  for (int r = rg; r < 64; r += 4){
    float lv = lab[((size_t)b*Sc + r)*Sc + c];
    double a;
    if (r == c) a = 0.0;
    else { a = 1e-5; if (r < L && c < L) a += exp((double)lv); }
    Md[r][c] = a;
  }
  if (rg == 0) rootv[c] = (c < L) ? exp((double)lab[((size_t)b*Sc + c)*Sc + c]) : 0.0;
  __syncthreads();
  {
    double ps = 0.0;
    for (int r = rg; r < 64; r += 4) ps += Md[r][c];
    part[rg][c] = ps;
  }
  __syncthreads();
  const double cs = part[0][c] + part[1][c] + part[2][c] + part[3][c];
  for (int r = rg; r < 64; r += 4){
    double v;
    if (r == 0) v = rootv[c];
    else { v = -Md[r][c]; if (r == c) v += cs + ((c >= L) ? 1.0 : 0.0); }
    Md[r][c] = v;
  }
  __syncthreads();

  double logdet = 0.0;
  for (int p = 0; p < 64; ++p){
    if (tid < 64){
      double v = (tid >= p) ? fabs(Md[tid][p]) : -1.0;
      int iv = tid;
      #pragma unroll
      for (int off=32; off>0; off>>=1){
        double ov = __shfl_xor(v, off);
        int    oi = __shfl_xor(iv, off);
        if (ov > v || (ov == v && oi < iv)) { v = ov; iv = oi; }
      }
      if (tid == 0) spiv = iv;
    }
    __syncthreads();
    const int piv = spiv;
    if (piv != p && tid < 64){
      double tmp = Md[p][tid]; Md[p][tid] = Md[piv][tid]; Md[piv][tid] = tmp;
    }
    __syncthreads();
    const double diag = Md[p][p];
    logdet += log(fabs(diag));
    if (c > p){
      for (int r = p + 1 + rg; r < 64; r += 4)
        Md[r][c] -= (Md[r][p] / diag) * Md[p][c];
    }
    __syncthreads();
  }
  if (tid == 0) out[(size_t)Bc*Tc*65*65 + b] = (float)logdet;
}

// pe = _expand_matrix(masked pt)
__global__ void k_out(const float* __restrict__ pt_acc, const float* __restrict__ btv,
                      const int* __restrict__ lens, float* __restrict__ out){
  const int idx = blockIdx.x*256 + threadIdx.x;
  if (idx >= Bc*Tc*65*65) return;
  const int cc = idx % 65; int tmp = idx / 65;
  const int rr = tmp % 65; tmp /= 65;
  const int t  = tmp % Tc; const int b = tmp / Tc;
  float v;
  if (rr == cc) v = 0.f;
  else if (cc == 0) v = NEGF;
  else {
    const int i = (rr == 0) ? (cc-1) : (rr-1);
    v = pt_val(pt_acc, btv, b, t, i, cc-1, lens[b]);
  }
  out[idx] = v;
}

__global__ void k_zero_out(float* out, int n){
  int i = blockIdx.x*256 + threadIdx.x;
  if (i < n) out[i] = 0.f;
}

// ---------------------------------------------------------------------------
extern "C" void kernel_launch(void* const* d_in, const int* in_sizes, int n_in,
                              void* d_out, int out_size, void* d_ws, size_t ws_size,
                              hipStream_t stream)
{
  (void)in_sizes; (void)n_in;
  const int*   lens  = (const int*)  d_in[2];
  const float* sv    = (const float*)d_in[3];
  const float* Wih_f = (const float*)d_in[5];
  const float* Whh_f = (const float*)d_in[6];
  const float* bih_f = (const float*)d_in[7];
  const float* bhh_f = (const float*)d_in[8];
  const float* Wih_b = (const float*)d_in[9];
  const float* Whh_b = (const float*)d_in[10];
  const float* bih_b = (const float*)d_in[11];
  const float* bhh_b = (const float*)d_in[12];
  const float* Wt    = (const float*)d_in[13];
  const float* btv   = (const float*)d_in[14];

  const size_t SVB  = (size_t)Bc*TRIc*Hc*2;       // 17.0 MB bf16
  const size_t WPB  = (size_t)2*16*128*1024*2;    // 8.39 MB bf16
  const size_t WTB  = (size_t)Tc*1024*2;          // 34.8 KB
  const size_t PT   = (size_t)Bc*Tc*Sc*Sc*4;      // 2.23 MB
  const size_t HB   = (size_t)2*4*8*64*Hc*2;      // 4.19 MB bf16
  const size_t CB   = (size_t)4*8*64*Hc*4;        // 8.39 MB fp32
  const size_t LAB  = (size_t)Bc*Sc*Sc*4;         // 131 KB
  const size_t NEED = SVB + WPB + WTB + PT + HB + CB + LAB + 8192;

  if (ws_size < NEED) {
    k_zero_out<<<dim3((out_size+255)/256), 256, 0, stream>>>((float*)d_out, out_size);
    return;
  }

  char* base = (char*)d_ws;
  size_t off = 0;
  auto take = [&](size_t bytes)->char*{
    char* r = base + off; off += (bytes + 255) & ~(size_t)255; return r; };

  __hip_bfloat16* svb = (__hip_bfloat16*)take(SVB);
  __hip_bfloat16* Wp  = (__hip_bfloat16*)take(WPB);
  __hip_bfloat16* Wtb = (__hip_bfloat16*)take(WTB);
  float* pt_acc = (float*)take(PT);
  __hip_bfloat16* H = (__hip_bfloat16*)take(HB);
  float* C   = (float*)take(CB);
  float* lab = (float*)take(LAB);

  (void)hipMemsetAsync(pt_acc, 0, PT + HB + CB, stream);

  k_cvt<<<dim3(8320), 256, 0, stream>>>(sv, svb, 2129920);
  k_pack<<<dim3(4096), 256, 0, stream>>>(Whh_f, Wih_f, Whh_b, Wih_b, Wp);
  k_cvt<<<dim3(17),   256, 0, stream>>>(Wt, Wtb, 4352);

  for (int k=0; k<Sc; k++)
    k_step3<<<dim3(16,4,4), 512, 0, stream>>>(Wp, bih_f, bhh_f, bih_b, bhh_b,
                                              svb, Wtb, lens, H, C, pt_acc, k);

  k_lse <<<dim3(128), 256, 0, stream>>>(pt_acc, btv, lens, lab);
  k_logz<<<dim3(Bc), 256, 0, stream>>>(lab, lens, (float*)d_out);
  k_out <<<dim3((Bc*Tc*65*65 + 255)/256), 256, 0, stream>>>(pt_acc, btv, lens, (float*)d_out);
}